// Round 2
// baseline (204.928 us; speedup 1.0000x reference)
//
#include <hip/hip_runtime.h>
#include <math.h>

// Performer (FAVOR+) causal attention. B=1, L=2048, D=512, H=8, DH=64, M=128.
// Round 15: fuse {chunksum, prefix, attn, out_gemm} into ONE 256-block
// mega-kernel with device-scope grid barriers (atomic arrive + relaxed spin +
// __threadfence for cross-XCD L2 wb/inv). The 4 back kernels were each ~1-3 us
// of real work but paid launch + CP-flush + tail overhead per boundary.
// Residency: 77.6KB LDS, 8 waves -> >=1 block/CU, 256 blocks <= 256 CUs.
// V^T staged in LDS by the chunksum phase is reused by the attn phase.

#define L       2048
#define DMODEL  512
#define NH      8
#define DH      64
#define M       128
#define CT      64          // chunk size
#define NC      (L/CT)      // 32 chunks per head
#define KEPS    1e-4f
#define DEPS    1e-6f
#define SCALE   0.2102241038134286f   // 512^-0.25
#define NCONST  0.08838834764831845f  // 128^-0.5
#define NBLK    256

// workspace layout (float offsets)
#define OFF_VB     0          // bf16 [l][512]
#define OFF_QPB    524288     // bf16 [h][l][m]
#define OFF_KPB    1572864
#define OFF_SSB    2621440    // bf16 [h][c][m*64+d]  (S), prefix in-place
#define OFF_SSZ    3670016    // fp32 [h][c][m]       (z), prefix in-place
#define OFF_CTX    3702784    // bf16 [l][512]
#define OFF_BAR    4227072    // 4 x unsigned grid-barrier counters
#define OFF_END    4227076

typedef short bf16x8 __attribute__((ext_vector_type(8)));
typedef float f32x4  __attribute__((ext_vector_type(4)));
typedef __bf16 bf2_t __attribute__((ext_vector_type(2)));
typedef unsigned short ushort_t;

__device__ __forceinline__ ushort_t f2bf(float f) {
    union { __bf16 b; ushort_t u; } cv;
    cv.b = (__bf16)f;               // v_cvt_pk_bf16_f32 (RNE)
    return cv.u;
}
__device__ __forceinline__ float bf2f(ushort_t u) {
    return __uint_as_float(((unsigned)u) << 16);
}
__device__ __forceinline__ unsigned pack2(float a, float b) {
    bf2_t v;
    v.x = (__bf16)a;
    v.y = (__bf16)b;                // pair -> single v_cvt_pk_bf16_f32
    union { bf2_t v; unsigned u; } cv;
    cv.v = v;
    return cv.u;
}
__device__ __forceinline__ void unpack8(uint4 u, ushort_t* e) {
    e[0] = (ushort_t)(u.x & 0xffff); e[1] = (ushort_t)(u.x >> 16);
    e[2] = (ushort_t)(u.y & 0xffff); e[3] = (ushort_t)(u.y >> 16);
    e[4] = (ushort_t)(u.z & 0xffff); e[5] = (ushort_t)(u.z >> 16);
    e[6] = (ushort_t)(u.w & 0xffff); e[7] = (ushort_t)(u.w >> 16);
}

// device-scope grid barrier. Writer side: __threadfence (buffer_wbl2) before
// arrive; reader side: relaxed spin (no repeated L2-inv) + __threadfence
// (buffer_inv) after release. Counters are per-phase, zeroed by qkvp_kernel.
__device__ __forceinline__ void grid_barrier(unsigned* bar) {
    __syncthreads();
    if (threadIdx.x == 0) {
        __threadfence();
        __hip_atomic_fetch_add(bar, 1u, __ATOMIC_ACQ_REL, __HIP_MEMORY_SCOPE_AGENT);
        while (__hip_atomic_load(bar, __ATOMIC_RELAXED, __HIP_MEMORY_SCOPE_AGENT) < (unsigned)NBLK)
            __builtin_amdgcn_s_sleep(2);
        __threadfence();
    }
    __syncthreads();
}

// ---- fused QKV projection + (for Q,K) feature map --------------------------
__global__ __launch_bounds__(256) void qkvp_kernel(
    const float* __restrict__ xq, const float* __restrict__ xk, const float* __restrict__ xv,
    const float* __restrict__ Wq, const float* __restrict__ bq,
    const float* __restrict__ Wk, const float* __restrict__ bk,
    const float* __restrict__ Wv, const float* __restrict__ bv,
    const float* __restrict__ RF,
    ushort_t* __restrict__ Vb, ushort_t* __restrict__ QPb, ushort_t* __restrict__ KPb,
    unsigned* __restrict__ bar)
{
    __shared__ __align__(16) char smem[24832];      // As8 8*65 + Bs8 8*129 uint4; aliased by RFTs
    __shared__ ushort_t Qt[64 * 136];               // 17.4 KB gemm tile (2 heads)
    __shared__ float ssq[128];
    uint4* As8 = (uint4*)smem;                      // [k8][row] stride 65
    uint4* Bs8 = (uint4*)(smem + 520 * 16);         // [k8][col] stride 129
    ushort_t* RFTs = (ushort_t*)smem;               // [m][72] used after gemm

    if (blockIdx.x == 0 && blockIdx.y == 0 && blockIdx.z == 0 && threadIdx.x < 4)
        bar[threadIdx.x] = 0u;                      // init mega-kernel barriers

    const int tid  = threadIdx.x;
    const int lane = tid & 63;
    const int wave = tid >> 6;
    const int quad = lane >> 4;
    const int l15  = lane & 15;
    const int z = blockIdx.z;
    const int isK = (z == 1);
    const int row0 = blockIdx.x * 64;
    const int col0 = blockIdx.y * 128;

    const float* X; const float* W; const float* bias;
    if (z == 0)      { X = xq; W = Wq; bias = bq; }
    else if (z == 1) { X = xk; W = Wk; bias = bk; }
    else             { X = xv; W = Wv; bias = bv; }

    f32x4 acc[4][2];
    const f32x4 z4 = {0.f, 0.f, 0.f, 0.f};
    #pragma unroll
    for (int i = 0; i < 4; ++i) { acc[i][0] = z4; acc[i][1] = z4; }

    uint4 ra[2], rb[4];
    auto loadA = [&](int ck) {
        #pragma unroll
        for (int it = 0; it < 2; ++it) {
            int t = tid + it * 256;
            int row = t >> 3, k8 = t & 7;
            const float4* gp = (const float4*)&X[(row0 + row) * DMODEL + ck * 64 + k8 * 8];
            float4 v0 = gp[0], v1 = gp[1];
            ra[it] = make_uint4(pack2(v0.x, v0.y), pack2(v0.z, v0.w),
                                pack2(v1.x, v1.y), pack2(v1.z, v1.w));
        }
    };
    auto loadB = [&](int ck) {
        #pragma unroll
        for (int it = 0; it < 4; ++it) {
            int t = tid + it * 256;
            int col = t >> 3, k8 = t & 7;
            const float4* gp = (const float4*)&W[(col0 + col) * DMODEL + ck * 64 + k8 * 8];
            float4 v0 = gp[0], v1 = gp[1];
            rb[it] = make_uint4(pack2(v0.x, v0.y), pack2(v0.z, v0.w),
                                pack2(v1.x, v1.y), pack2(v1.z, v1.w));
        }
    };

    loadA(0); loadB(0);
    const int wn = wave;
    for (int ck = 0; ck < 8; ++ck) {
        __syncthreads();
        #pragma unroll
        for (int it = 0; it < 2; ++it) {
            int t = tid + it * 256;
            As8[(t & 7) * 65 + (t >> 3)] = ra[it];
        }
        #pragma unroll
        for (int it = 0; it < 4; ++it) {
            int t = tid + it * 256;
            Bs8[(t & 7) * 129 + (t >> 3)] = rb[it];
        }
        __syncthreads();
        if (ck < 7) { loadA(ck + 1); loadB(ck + 1); }
        const bf16x8* Av = (const bf16x8*)As8;
        const bf16x8* Bv = (const bf16x8*)Bs8;
        #pragma unroll
        for (int kc = 0; kc < 2; ++kc) {
            const int k8 = kc * 4 + quad;
            bf16x8 af[4], bfr[2];
            #pragma unroll
            for (int i = 0; i < 4; ++i) af[i] = Av[k8 * 65 + i * 16 + l15];
            #pragma unroll
            for (int j = 0; j < 2; ++j) bfr[j] = Bv[k8 * 129 + wn * 32 + j * 16 + l15];
            #pragma unroll
            for (int i = 0; i < 4; ++i)
                #pragma unroll
                for (int j = 0; j < 2; ++j)
                    acc[i][j] = __builtin_amdgcn_mfma_f32_16x16x32_bf16(af[i], bfr[j], acc[i][j], 0, 0, 0);
        }
    }

    if (z == 2) {   // V epilogue -> global bf16
        #pragma unroll
        for (int i = 0; i < 4; ++i)
            #pragma unroll
            for (int j = 0; j < 2; ++j) {
                int c = col0 + wn * 32 + j * 16 + l15;
                float bv_ = bias[c];
                #pragma unroll
                for (int reg = 0; reg < 4; ++reg) {
                    int r = row0 + i * 16 + quad * 4 + reg;
                    Vb[r * DMODEL + c] = f2bf(acc[i][j][reg] + bv_);
                }
            }
        return;
    }

    // ---- Q/K epilogue -> LDS tile ----
    #pragma unroll
    for (int i = 0; i < 4; ++i)
        #pragma unroll
        for (int j = 0; j < 2; ++j) {
            int c = wn * 32 + j * 16 + l15;                  // 0..127 (2 heads)
            float bv_ = bias[col0 + c];
            #pragma unroll
            for (int reg = 0; reg < 4; ++reg) {
                int r = i * 16 + quad * 4 + reg;             // 0..63
                Qt[r * 136 + c] = f2bf(acc[i][j][reg] + bv_);
            }
        }
    __syncthreads();     // all As8/Bs8 reads done; safe to alias with RFTs

    {   // stage RF -> RFTs[m][d] bf16 with SCALE folded
        int m = tid & 127, half = tid >> 7;
        #pragma unroll
        for (int j = 0; j < 32; ++j) {
            int d = half * 32 + j;
            RFTs[m * 72 + d] = f2bf(SCALE * RF[d * M + m]);
        }
    }
    if (isK && tid < 128) {      // per (head-half, row) sumsq
        int hh = tid >> 6, row = tid & 63;
        float s = 0.f;
        #pragma unroll
        for (int d = 0; d < DH; ++d) {
            float v = bf2f(Qt[row * 136 + hh * 64 + d]);
            s += v * v;
        }
        ssq[tid] = s;
    }
    __syncthreads();

    // ---- primes MFMA: per wave (head-half hh, m-half mh), 64 rows x 64 m ----
    const int hh = wave >> 1, mh = wave & 1;
    const float s2h = 0.5f * SCALE * SCALE;
    f32x4 pac[4][4];
    #pragma unroll
    for (int i = 0; i < 4; ++i)
        #pragma unroll
        for (int j = 0; j < 4; ++j) pac[i][j] = z4;
    #pragma unroll
    for (int kc = 0; kc < 2; ++kc) {
        bf16x8 af[4], bfr[4];
        #pragma unroll
        for (int i = 0; i < 4; ++i)
            af[i] = *(const bf16x8*)&Qt[(i * 16 + l15) * 136 + hh * 64 + kc * 32 + quad * 8];
        #pragma unroll
        for (int j = 0; j < 4; ++j)
            bfr[j] = *(const bf16x8*)&RFTs[(mh * 64 + j * 16 + l15) * 72 + kc * 32 + quad * 8];
        #pragma unroll
        for (int i = 0; i < 4; ++i)
            #pragma unroll
            for (int j = 0; j < 4; ++j)
                pac[i][j] = __builtin_amdgcn_mfma_f32_16x16x32_bf16(af[i], bfr[j], pac[i][j], 0, 0, 0);
    }

    ushort_t* dst = isK ? KPb : QPb;
    const int hgl = blockIdx.y * 2 + hh;
    #pragma unroll
    for (int i = 0; i < 4; ++i)
        #pragma unroll
        for (int reg = 0; reg < 4; ++reg) {
            int row = i * 16 + quad * 4 + reg;
            float off = isK ? (-s2h * ssq[hh * 64 + row]) : 0.f;
            #pragma unroll
            for (int j = 0; j < 4; ++j) {
                int m = mh * 64 + j * 16 + l15;
                float p = pac[i][j][reg] + off;
                dst[((long)hgl * L + row0 + row) * M + m] = f2bf(NCONST * (__expf(p) + KEPS));
            }
        }
}

// --------------- fused mega-kernel: chunksum -> prefix -> attn -> out -------
__global__ __launch_bounds__(512) void mega_kernel(
    const ushort_t* __restrict__ QPb, const ushort_t* __restrict__ KPb,
    const ushort_t* __restrict__ Vb,
    ushort_t* __restrict__ SSb, float* __restrict__ SSz,
    ushort_t* __restrict__ ctxb,
    const float* __restrict__ Wo, const float* __restrict__ bo,
    float* __restrict__ out, unsigned* __restrict__ bar)
{
    // LDS union (77568 B):
    //  [Vt 11520][Qp 17408][Kp 17408][St 21760][Am 9216][den 256]
    //  chunksum Kt (18432) aliases Qp..; out_gemm As8/Bs8 (20736) alias base.
    __shared__ __align__(16) char SM[77568];
    ushort_t* Vt = (ushort_t*)(SM);               // [80][72]; row 64 = ones
    ushort_t* Qp = (ushort_t*)(SM + 11520);       // [64][136]
    ushort_t* Kp = (ushort_t*)(SM + 28928);       // [64][136]
    ushort_t* St = (ushort_t*)(SM + 46336);       // [80][136]; row 64 = z
    ushort_t* Am = (ushort_t*)(SM + 68096);       // [64][72]
    float*    den = (float*)(SM + 77312);         // [64]
    ushort_t* Kt = (ushort_t*)(SM + 11520);       // [128][72] (phase A alias)

    const int tid  = threadIdx.x;
    const int lane = tid & 63;
    const int wave = tid >> 6;              // 0..7
    const int quad = lane >> 4;
    const int l15  = lane & 15;
    const int bid  = blockIdx.x;
    const int c = bid & 31, h = bid >> 5;
    const f32x4 z4 = {0.f, 0.f, 0.f, 0.f};

    // ================= phase A: chunk sums S = K'^T V, z ====================
    {
        const ushort_t* kr = &KPb[((long)(h * L) + c * CT + lane) * M];
        #pragma unroll
        for (int it = 0; it < 2; ++it) {
            int mo = it * 8 + wave;                 // m-octet 0..15
            uint4 u = *(const uint4*)&kr[mo * 8];
            ushort_t e[8]; unpack8(u, e);
            #pragma unroll
            for (int j = 0; j < 8; ++j) Kt[(mo * 8 + j) * 72 + lane] = e[j];
        }
        const ushort_t* vr = &Vb[(c * CT + lane) * DMODEL + h * DH];
        {
            int dd = wave;                          // d-octet 0..7
            uint4 u = *(const uint4*)&vr[dd * 8];
            ushort_t e[8]; unpack8(u, e);
            #pragma unroll
            for (int j = 0; j < 8; ++j) Vt[(dd * 8 + j) * 72 + lane] = e[j];
        }
        if (wave == 0) Vt[64 * 72 + lane] = 0x3F80;     // bf16 1.0 (ones row)
        if (wave == 1) {
            #pragma unroll
            for (int r = 65; r < 80; ++r) Vt[r * 72 + lane] = 0;
        }
        __syncthreads();

        f32x4 acc[5];
        #pragma unroll
        for (int j = 0; j < 5; ++j) acc[j] = z4;
        #pragma unroll
        for (int kt = 0; kt < 2; ++kt) {
            bf16x8 af = *(const bf16x8*)&Kt[(wave * 16 + l15) * 72 + kt * 32 + quad * 8];
            #pragma unroll
            for (int j = 0; j < 5; ++j) {
                bf16x8 bfr = *(const bf16x8*)&Vt[(j * 16 + l15) * 72 + kt * 32 + quad * 8];
                acc[j] = __builtin_amdgcn_mfma_f32_16x16x32_bf16(af, bfr, acc[j], 0, 0, 0);
            }
        }
        ushort_t* outS = SSb + (long)(h * NC + c) * 8192;
        #pragma unroll
        for (int reg = 0; reg < 4; ++reg) {
            int m = wave * 16 + quad * 4 + reg;
            #pragma unroll
            for (int j = 0; j < 4; ++j)
                outS[m * 64 + j * 16 + l15] = f2bf(acc[j][reg]);
            if (l15 == 0) SSz[(h * NC + c) * M + m] = acc[4][reg];
        }
    }
    grid_barrier(bar + 0);

    // ================= phase B: exclusive prefix over chunks ================
    {
        if (tid < 256) {                 // S-scan: this block handles 256 idx
            const int idx = c * 256 + tid;
            const long base = (long)h * NC * 8192 + idx;
            ushort_t v[NC];
            #pragma unroll
            for (int cc = 0; cc < NC; ++cc) v[cc] = SSb[base + (long)cc * 8192];
            float run = 0.f;
            #pragma unroll
            for (int cc = 0; cc < NC; ++cc) {
                SSb[base + (long)cc * 8192] = f2bf(run);
                run += bf2f(v[cc]);
            }
        } else if (c == 0 && tid < 384) {   // z-scan: blocks c==0, 128 threads
            const int m = tid - 256;
            float v[NC];
            #pragma unroll
            for (int cc = 0; cc < NC; ++cc) v[cc] = SSz[(h * NC + cc) * M + m];
            float run = 0.f;
            #pragma unroll
            for (int cc = 0; cc < NC; ++cc) {
                SSz[(h * NC + cc) * M + m] = run;
                run += v[cc];
            }
        }
    }
    grid_barrier(bar + 1);

    // ================= phase C: causal kernel attention =====================
    {
        const int iw = wave & 3;            // rows tile (16 rows)
        const int nh = wave >> 2;           // cols half (32 cols)

        for (int t = tid; t < 2048; t += 512) {          // Qp/Kp stage
            int mat = t >> 10, r = (t >> 4) & 63, c8 = t & 15;
            const ushort_t* src = mat ? KPb : QPb;
            uint4 u = *(const uint4*)&src[((long)(h * L) + c * CT + r) * M + c8 * 8];
            ushort_t* dst = mat ? Kp : Qp;
            *(uint4*)&dst[r * 136 + c8 * 8] = u;
        }
        {   // St[d][m] from S[m][d]  (Vt is still live from phase A)
            const ushort_t* ssb = SSb + (long)(h * NC + c) * 8192;
            int m = tid & 127, dg = tid >> 7;    // dg 0..3
            #pragma unroll
            for (int it = 0; it < 2; ++it) {
                int dd = it * 4 + dg;            // d-octet 0..7
                uint4 u = *(const uint4*)&ssb[m * 64 + dd * 8];
                ushort_t e[8]; unpack8(u, e);
                #pragma unroll
                for (int j = 0; j < 8; ++j) St[(dd * 8 + j) * 136 + m] = e[j];
            }
        }
        if (tid < 128) St[64 * 136 + tid] = f2bf(SSz[(h * NC + c) * M + tid]);  // z row
        for (int t = tid; t < 15 * 136; t += 512) St[65 * 136 + t] = 0;         // pad
        __syncthreads();

        // phase C1: scores
        f32x4 acc1[2];
        acc1[0] = z4; acc1[1] = z4;
        #pragma unroll
        for (int kt = 0; kt < 4; ++kt) {
            bf16x8 af = *(const bf16x8*)&Qp[(iw * 16 + l15) * 136 + kt * 32 + quad * 8];
            #pragma unroll
            for (int jt = 0; jt < 2; ++jt) {
                bf16x8 bf = *(const bf16x8*)&Kp[(nh * 32 + jt * 16 + l15) * 136 + kt * 32 + quad * 8];
                acc1[jt] = __builtin_amdgcn_mfma_f32_16x16x32_bf16(af, bf, acc1[jt], 0, 0, 0);
            }
        }
        #pragma unroll
        for (int jt = 0; jt < 2; ++jt) {
            int col = nh * 32 + jt * 16 + l15;
            #pragma unroll
            for (int reg = 0; reg < 4; ++reg) {
                int row = iw * 16 + quad * 4 + reg;
                Am[row * 72 + col] = f2bf((col <= row) ? acc1[jt][reg] : 0.f);
            }
        }
        __syncthreads();

        // phase C2: N = [Am|Q'] @ [V;S], den = column 64
        f32x4 acc2[2], acc3;
        acc2[0] = z4; acc2[1] = z4; acc3 = z4;
        #pragma unroll
        for (int kt = 0; kt < 6; ++kt) {
            bf16x8 af = (kt < 2)
                ? *(const bf16x8*)&Am[(iw * 16 + l15) * 72 + kt * 32 + quad * 8]
                : *(const bf16x8*)&Qp[(iw * 16 + l15) * 136 + (kt - 2) * 32 + quad * 8];
            #pragma unroll
            for (int jt = 0; jt < 2; ++jt) {
                int n = nh * 32 + jt * 16 + l15;
                bf16x8 bf = (kt < 2)
                    ? *(const bf16x8*)&Vt[n * 72 + kt * 32 + quad * 8]
                    : *(const bf16x8*)&St[n * 136 + (kt - 2) * 32 + quad * 8];
                acc2[jt] = __builtin_amdgcn_mfma_f32_16x16x32_bf16(af, bf, acc2[jt], 0, 0, 0);
            }
            if (nh == 0) {
                bf16x8 bz = (kt < 2)
                    ? *(const bf16x8*)&Vt[(64 + l15) * 72 + kt * 32 + quad * 8]
                    : *(const bf16x8*)&St[(64 + l15) * 136 + (kt - 2) * 32 + quad * 8];
                acc3 = __builtin_amdgcn_mfma_f32_16x16x32_bf16(af, bz, acc3, 0, 0, 0);
            }
        }
        if (nh == 0 && l15 == 0) {
            #pragma unroll
            for (int reg = 0; reg < 4; ++reg)
                den[iw * 16 + quad * 4 + reg] = acc3[reg];
        }
        __syncthreads();
        #pragma unroll
        for (int jt = 0; jt < 2; ++jt) {
            int d = nh * 32 + jt * 16 + l15;
            #pragma unroll
            for (int reg = 0; reg < 4; ++reg) {
                int row = iw * 16 + quad * 4 + reg;
                ctxb[(c * CT + row) * DMODEL + h * DH + d] = f2bf(acc2[jt][reg] / (den[row] + DEPS));
            }
        }
    }
    grid_barrier(bar + 2);

    // ================= phase D: output GEMM =================================
    {
        const int ro = bid & 63, co = bid >> 6;
        const int row0 = ro * 32, col0 = co * 128;
        uint4* As8 = (uint4*)SM;                  // [k8][row] stride 33
        uint4* Bs8 = (uint4*)(SM + 4224);         // [k8][col] stride 129
        const int wn = wave & 3, rh = wave >> 2;

        f32x4 acc[2]; acc[0] = z4; acc[1] = z4;
        uint4 ra, rb[2];
        auto loadA2 = [&](int ck) {
            if (tid < 256) {
                int row = tid >> 3, k8 = tid & 7;
                ra = *(const uint4*)&ctxb[(row0 + row) * DMODEL + ck * 64 + k8 * 8];
            }
        };
        auto loadB2 = [&](int ck) {
            #pragma unroll
            for (int it = 0; it < 2; ++it) {
                int bt = tid + it * 512;
                int col = bt >> 3, k8 = bt & 7;
                const float4* gp = (const float4*)&Wo[(col0 + col) * DMODEL + ck * 64 + k8 * 8];
                float4 v0 = gp[0], v1 = gp[1];
                rb[it] = make_uint4(pack2(v0.x, v0.y), pack2(v0.z, v0.w),
                                    pack2(v1.x, v1.y), pack2(v1.z, v1.w));
            }
        };

        loadA2(0); loadB2(0);
        for (int ck = 0; ck < 8; ++ck) {
            __syncthreads();
            if (tid < 256) As8[(tid & 7) * 33 + (tid >> 3)] = ra;
            #pragma unroll
            for (int it = 0; it < 2; ++it) {
                int bt = tid + it * 512;
                Bs8[(bt & 7) * 129 + (bt >> 3)] = rb[it];
            }
            __syncthreads();
            if (ck < 7) { loadA2(ck + 1); loadB2(ck + 1); }
            const bf16x8* Av = (const bf16x8*)As8;
            const bf16x8* Bv = (const bf16x8*)Bs8;
            #pragma unroll
            for (int kc = 0; kc < 2; ++kc) {
                const int k8 = kc * 4 + quad;
                bf16x8 af = Av[k8 * 33 + rh * 16 + l15];
                bf16x8 b0 = Bv[k8 * 129 + wn * 32 + l15];
                bf16x8 b1 = Bv[k8 * 129 + wn * 32 + 16 + l15];
                acc[0] = __builtin_amdgcn_mfma_f32_16x16x32_bf16(af, b0, acc[0], 0, 0, 0);
                acc[1] = __builtin_amdgcn_mfma_f32_16x16x32_bf16(af, b1, acc[1], 0, 0, 0);
            }
        }
        #pragma unroll
        for (int j = 0; j < 2; ++j) {
            int cc = col0 + wn * 32 + j * 16 + l15;
            float bv_ = bo[cc];
            #pragma unroll
            for (int reg = 0; reg < 4; ++reg) {
                int r = row0 + rh * 16 + quad * 4 + reg;
                out[r * DMODEL + cc] = acc[j][reg] + bv_;
            }
        }
    }
}

extern "C" void kernel_launch(void* const* d_in, const int* in_sizes, int n_in,
                              void* d_out, int out_size, void* d_ws, size_t ws_size,
                              hipStream_t stream)
{
    const float* query = (const float*)d_in[0];
    const float* key_  = (const float*)d_in[1];
    const float* value = (const float*)d_in[2];
    const float* Wq = (const float*)d_in[3];
    const float* bq = (const float*)d_in[4];
    const float* Wk = (const float*)d_in[5];
    const float* bk = (const float*)d_in[6];
    const float* Wv = (const float*)d_in[7];
    const float* bv = (const float*)d_in[8];
    const float* Wo = (const float*)d_in[9];
    const float* bo = (const float*)d_in[10];
    const float* RF = (const float*)d_in[11];

    float* ws = (float*)d_ws;
    ushort_t* Vb   = (ushort_t*)(ws + OFF_VB);
    ushort_t* QPb  = (ushort_t*)(ws + OFF_QPB);
    ushort_t* KPb  = (ushort_t*)(ws + OFF_KPB);
    ushort_t* SSb  = (ushort_t*)(ws + OFF_SSB);
    float* SSz     = ws + OFF_SSZ;
    ushort_t* CTXB = (ushort_t*)(ws + OFF_CTX);
    unsigned* bar  = (unsigned*)(ws + OFF_BAR);

    qkvp_kernel<<<dim3(32, 4, 3), 256, 0, stream>>>(query, key_, value,
                                                    Wq, bq, Wk, bk, Wv, bv, RF,
                                                    Vb, QPb, KPb, bar);
    mega_kernel<<<dim3(NBLK), 512, 0, stream>>>(QPb, KPb, Vb, SSb, SSz, CTXB,
                                                Wo, bo, (float*)d_out, bar);
}

// Round 4
// 135.355 us; speedup vs baseline: 1.5140x; 1.5140x over previous
//
#include <hip/hip_runtime.h>
#include <math.h>

// Performer (FAVOR+) causal attention. B=1, L=2048, D=512, H=8, DH=64, M=128.
// Round 17: mega-kernel with FENCE-FREE barrier, coherent path via COMPILER
// atomics (relaxed, agent scope -> sc0 sc1 cache-bypass emitted by LLVM, no
// inline-asm VMEM). R15's threadfence barrier cost ~100us of buffer_wbl2/inv;
// R16's hand-rolled asm sc0sc1 path crashed. All cross-barrier data (SSb, SSz,
// ctxb) moves through __hip_atomic_load/store at the Infinity Cache (the
// coherent point); barrier release is one s_waitcnt vmcnt(0) + relaxed
// atomic arrive + relaxed spin. Pre-launch data keeps cached loads (dispatch
// acquire invalidates L1/L2).

#define L       2048
#define DMODEL  512
#define NH      8
#define DH      64
#define M       128
#define CT      64          // chunk size
#define NC      (L/CT)      // 32 chunks per head
#define KEPS    1e-4f
#define DEPS    1e-6f
#define SCALE   0.2102241038134286f   // 512^-0.25
#define NCONST  0.08838834764831845f  // 128^-0.5
#define NBLK    256

// workspace layout (float offsets)
#define OFF_VB     0          // bf16 [l][512]
#define OFF_QPB    524288     // bf16 [h][l][m]
#define OFF_KPB    1572864
#define OFF_SSB    2621440    // bf16 [h][c][m*64+d]  (S), prefix in-place
#define OFF_SSZ    3670016    // fp32 [h][c][m]       (z), prefix in-place
#define OFF_CTX    3702784    // bf16 [l][512]
#define OFF_BAR    4227072    // 4 x unsigned grid-barrier counters
#define OFF_END    4227076

typedef short bf16x8 __attribute__((ext_vector_type(8)));
typedef float f32x4  __attribute__((ext_vector_type(4)));
typedef __bf16 bf2_t __attribute__((ext_vector_type(2)));
typedef unsigned short ushort_t;
typedef unsigned long long u64_t;

__device__ __forceinline__ ushort_t f2bf(float f) {
    union { __bf16 b; ushort_t u; } cv;
    cv.b = (__bf16)f;               // v_cvt_pk_bf16_f32 (RNE)
    return cv.u;
}
__device__ __forceinline__ float bf2f(ushort_t u) {
    return __uint_as_float(((unsigned)u) << 16);
}
__device__ __forceinline__ unsigned pack2(float a, float b) {
    bf2_t v;
    v.x = (__bf16)a;
    v.y = (__bf16)b;                // pair -> single v_cvt_pk_bf16_f32
    union { bf2_t v; unsigned u; } cv;
    cv.v = v;
    return cv.u;
}
__device__ __forceinline__ void unpack8(uint4 u, ushort_t* e) {
    e[0] = (ushort_t)(u.x & 0xffff); e[1] = (ushort_t)(u.x >> 16);
    e[2] = (ushort_t)(u.y & 0xffff); e[3] = (ushort_t)(u.y >> 16);
    e[4] = (ushort_t)(u.z & 0xffff); e[5] = (ushort_t)(u.z >> 16);
    e[6] = (ushort_t)(u.w & 0xffff); e[7] = (ushort_t)(u.w >> 16);
}

// ---- coherent (Infinity-Cache) access path: compiler-emitted sc bits -------
__device__ __forceinline__ unsigned coh_ld32(const void* p) {
    return __hip_atomic_load((const unsigned*)p, __ATOMIC_RELAXED, __HIP_MEMORY_SCOPE_AGENT);
}
__device__ __forceinline__ u64_t coh_ld64(const void* p) {
    return __hip_atomic_load((const u64_t*)p, __ATOMIC_RELAXED, __HIP_MEMORY_SCOPE_AGENT);
}
__device__ __forceinline__ void coh_st32(void* p, unsigned v) {
    __hip_atomic_store((unsigned*)p, v, __ATOMIC_RELAXED, __HIP_MEMORY_SCOPE_AGENT);
}
__device__ __forceinline__ void coh_st16(void* p, ushort_t v) {
    __hip_atomic_store((ushort_t*)p, v, __ATOMIC_RELAXED, __HIP_MEMORY_SCOPE_AGENT);
}

// Fence-free device barrier: cross-barrier data is already at the coherent
// point (sc-bit atomics), so release = per-wave vmcnt(0); arrive/spin relaxed.
__device__ __forceinline__ void grid_barrier(unsigned* bar) {
    asm volatile("s_waitcnt vmcnt(0)" ::: "memory");   // per-wave store-ack
    __syncthreads();
    if (threadIdx.x == 0) {
        __hip_atomic_fetch_add(bar, 1u, __ATOMIC_RELAXED, __HIP_MEMORY_SCOPE_AGENT);
        while (__hip_atomic_load(bar, __ATOMIC_RELAXED, __HIP_MEMORY_SCOPE_AGENT) < (unsigned)NBLK)
            __builtin_amdgcn_s_sleep(1);
    }
    __syncthreads();
}

// ---- fused QKV projection + (for Q,K) feature map --------------------------
__global__ __launch_bounds__(256) void qkvp_kernel(
    const float* __restrict__ xq, const float* __restrict__ xk, const float* __restrict__ xv,
    const float* __restrict__ Wq, const float* __restrict__ bq,
    const float* __restrict__ Wk, const float* __restrict__ bk,
    const float* __restrict__ Wv, const float* __restrict__ bv,
    const float* __restrict__ RF,
    ushort_t* __restrict__ Vb, ushort_t* __restrict__ QPb, ushort_t* __restrict__ KPb,
    unsigned* __restrict__ bar)
{
    __shared__ __align__(16) char smem[24832];      // As8 8*65 + Bs8 8*129 uint4; aliased by RFTs
    __shared__ ushort_t Qt[64 * 136];               // 17.4 KB gemm tile (2 heads)
    __shared__ float ssq[128];
    uint4* As8 = (uint4*)smem;                      // [k8][row] stride 65
    uint4* Bs8 = (uint4*)(smem + 520 * 16);         // [k8][col] stride 129
    ushort_t* RFTs = (ushort_t*)smem;               // [m][72] used after gemm

    if (blockIdx.x == 0 && blockIdx.y == 0 && blockIdx.z == 0 && threadIdx.x < 4)
        bar[threadIdx.x] = 0u;                      // init mega-kernel barriers

    const int tid  = threadIdx.x;
    const int lane = tid & 63;
    const int wave = tid >> 6;
    const int quad = lane >> 4;
    const int l15  = lane & 15;
    const int z = blockIdx.z;
    const int isK = (z == 1);
    const int row0 = blockIdx.x * 64;
    const int col0 = blockIdx.y * 128;

    const float* X; const float* W; const float* bias;
    if (z == 0)      { X = xq; W = Wq; bias = bq; }
    else if (z == 1) { X = xk; W = Wk; bias = bk; }
    else             { X = xv; W = Wv; bias = bv; }

    f32x4 acc[4][2];
    const f32x4 z4 = {0.f, 0.f, 0.f, 0.f};
    #pragma unroll
    for (int i = 0; i < 4; ++i) { acc[i][0] = z4; acc[i][1] = z4; }

    uint4 ra[2], rb[4];
    auto loadA = [&](int ck) {
        #pragma unroll
        for (int it = 0; it < 2; ++it) {
            int t = tid + it * 256;
            int row = t >> 3, k8 = t & 7;
            const float4* gp = (const float4*)&X[(row0 + row) * DMODEL + ck * 64 + k8 * 8];
            float4 v0 = gp[0], v1 = gp[1];
            ra[it] = make_uint4(pack2(v0.x, v0.y), pack2(v0.z, v0.w),
                                pack2(v1.x, v1.y), pack2(v1.z, v1.w));
        }
    };
    auto loadB = [&](int ck) {
        #pragma unroll
        for (int it = 0; it < 4; ++it) {
            int t = tid + it * 256;
            int col = t >> 3, k8 = t & 7;
            const float4* gp = (const float4*)&W[(col0 + col) * DMODEL + ck * 64 + k8 * 8];
            float4 v0 = gp[0], v1 = gp[1];
            rb[it] = make_uint4(pack2(v0.x, v0.y), pack2(v0.z, v0.w),
                                pack2(v1.x, v1.y), pack2(v1.z, v1.w));
        }
    };

    loadA(0); loadB(0);
    const int wn = wave;
    for (int ck = 0; ck < 8; ++ck) {
        __syncthreads();
        #pragma unroll
        for (int it = 0; it < 2; ++it) {
            int t = tid + it * 256;
            As8[(t & 7) * 65 + (t >> 3)] = ra[it];
        }
        #pragma unroll
        for (int it = 0; it < 4; ++it) {
            int t = tid + it * 256;
            Bs8[(t & 7) * 129 + (t >> 3)] = rb[it];
        }
        __syncthreads();
        if (ck < 7) { loadA(ck + 1); loadB(ck + 1); }
        const bf16x8* Av = (const bf16x8*)As8;
        const bf16x8* Bv = (const bf16x8*)Bs8;
        #pragma unroll
        for (int kc = 0; kc < 2; ++kc) {
            const int k8 = kc * 4 + quad;
            bf16x8 af[4], bfr[2];
            #pragma unroll
            for (int i = 0; i < 4; ++i) af[i] = Av[k8 * 65 + i * 16 + l15];
            #pragma unroll
            for (int j = 0; j < 2; ++j) bfr[j] = Bv[k8 * 129 + wn * 32 + j * 16 + l15];
            #pragma unroll
            for (int i = 0; i < 4; ++i)
                #pragma unroll
                for (int j = 0; j < 2; ++j)
                    acc[i][j] = __builtin_amdgcn_mfma_f32_16x16x32_bf16(af[i], bfr[j], acc[i][j], 0, 0, 0);
        }
    }

    if (z == 2) {   // V epilogue -> global bf16
        #pragma unroll
        for (int i = 0; i < 4; ++i)
            #pragma unroll
            for (int j = 0; j < 2; ++j) {
                int c = col0 + wn * 32 + j * 16 + l15;
                float bv_ = bias[c];
                #pragma unroll
                for (int reg = 0; reg < 4; ++reg) {
                    int r = row0 + i * 16 + quad * 4 + reg;
                    Vb[r * DMODEL + c] = f2bf(acc[i][j][reg] + bv_);
                }
            }
        return;
    }

    // ---- Q/K epilogue -> LDS tile ----
    #pragma unroll
    for (int i = 0; i < 4; ++i)
        #pragma unroll
        for (int j = 0; j < 2; ++j) {
            int c = wn * 32 + j * 16 + l15;                  // 0..127 (2 heads)
            float bv_ = bias[col0 + c];
            #pragma unroll
            for (int reg = 0; reg < 4; ++reg) {
                int r = i * 16 + quad * 4 + reg;             // 0..63
                Qt[r * 136 + c] = f2bf(acc[i][j][reg] + bv_);
            }
        }
    __syncthreads();     // all As8/Bs8 reads done; safe to alias with RFTs

    {   // stage RF -> RFTs[m][d] bf16 with SCALE folded
        int m = tid & 127, half = tid >> 7;
        #pragma unroll
        for (int j = 0; j < 32; ++j) {
            int d = half * 32 + j;
            RFTs[m * 72 + d] = f2bf(SCALE * RF[d * M + m]);
        }
    }
    if (isK && tid < 128) {      // per (head-half, row) sumsq
        int hh = tid >> 6, row = tid & 63;
        float s = 0.f;
        #pragma unroll
        for (int d = 0; d < DH; ++d) {
            float v = bf2f(Qt[row * 136 + hh * 64 + d]);
            s += v * v;
        }
        ssq[tid] = s;
    }
    __syncthreads();

    // ---- primes MFMA: per wave (head-half hh, m-half mh), 64 rows x 64 m ----
    const int hh = wave >> 1, mh = wave & 1;
    const float s2h = 0.5f * SCALE * SCALE;
    f32x4 pac[4][4];
    #pragma unroll
    for (int i = 0; i < 4; ++i)
        #pragma unroll
        for (int j = 0; j < 4; ++j) pac[i][j] = z4;
    #pragma unroll
    for (int kc = 0; kc < 2; ++kc) {
        bf16x8 af[4], bfr[4];
        #pragma unroll
        for (int i = 0; i < 4; ++i)
            af[i] = *(const bf16x8*)&Qt[(i * 16 + l15) * 136 + hh * 64 + kc * 32 + quad * 8];
        #pragma unroll
        for (int j = 0; j < 4; ++j)
            bfr[j] = *(const bf16x8*)&RFTs[(mh * 64 + j * 16 + l15) * 72 + kc * 32 + quad * 8];
        #pragma unroll
        for (int i = 0; i < 4; ++i)
            #pragma unroll
            for (int j = 0; j < 4; ++j)
                pac[i][j] = __builtin_amdgcn_mfma_f32_16x16x32_bf16(af[i], bfr[j], pac[i][j], 0, 0, 0);
    }

    ushort_t* dst = isK ? KPb : QPb;
    const int hgl = blockIdx.y * 2 + hh;
    #pragma unroll
    for (int i = 0; i < 4; ++i)
        #pragma unroll
        for (int reg = 0; reg < 4; ++reg) {
            int row = i * 16 + quad * 4 + reg;
            float off = isK ? (-s2h * ssq[hh * 64 + row]) : 0.f;
            #pragma unroll
            for (int j = 0; j < 4; ++j) {
                int m = mh * 64 + j * 16 + l15;
                float p = pac[i][j][reg] + off;
                dst[((long)hgl * L + row0 + row) * M + m] = f2bf(NCONST * (__expf(p) + KEPS));
            }
        }
}

// --------------- fused mega-kernel: chunksum -> prefix -> attn -> out -------
__global__ __launch_bounds__(512) void mega_kernel(
    const ushort_t* __restrict__ QPb, const ushort_t* __restrict__ KPb,
    const ushort_t* __restrict__ Vb,
    ushort_t* __restrict__ SSb, float* __restrict__ SSz,
    ushort_t* __restrict__ ctxb,
    const float* __restrict__ Wo, const float* __restrict__ bo,
    float* __restrict__ out, unsigned* __restrict__ bar)
{
    // LDS union (77568 B):
    //  [Vt 11520][Qp 17408][Kp 17408][St 21760][Am 9216][den 256]
    //  chunksum Kt (18432) aliases Qp..; out_gemm As8/Bs8 (20736) alias base.
    __shared__ __align__(16) char SM[77568];
    ushort_t* Vt = (ushort_t*)(SM);               // [80][72]; row 64 = ones
    ushort_t* Qp = (ushort_t*)(SM + 11520);       // [64][136]
    ushort_t* Kp = (ushort_t*)(SM + 28928);       // [64][136]
    ushort_t* St = (ushort_t*)(SM + 46336);       // [80][136]; row 64 = z
    ushort_t* Am = (ushort_t*)(SM + 68096);       // [64][72]
    float*    den = (float*)(SM + 77312);         // [64]
    ushort_t* Kt = (ushort_t*)(SM + 11520);       // [128][72] (phase A alias)

    const int tid  = threadIdx.x;
    const int lane = tid & 63;
    const int wave = tid >> 6;              // 0..7
    const int quad = lane >> 4;
    const int l15  = lane & 15;
    const int bid  = blockIdx.x;
    const int c = bid & 31, h = bid >> 5;
    const f32x4 z4 = {0.f, 0.f, 0.f, 0.f};

    // ================= phase A: chunk sums S = K'^T V, z ====================
    {
        const ushort_t* kr = &KPb[((long)(h * L) + c * CT + lane) * M];
        #pragma unroll
        for (int it = 0; it < 2; ++it) {
            int mo = it * 8 + wave;                 // m-octet 0..15
            uint4 u = *(const uint4*)&kr[mo * 8];
            ushort_t e[8]; unpack8(u, e);
            #pragma unroll
            for (int j = 0; j < 8; ++j) Kt[(mo * 8 + j) * 72 + lane] = e[j];
        }
        const ushort_t* vr = &Vb[(c * CT + lane) * DMODEL + h * DH];
        {
            int dd = wave;                          // d-octet 0..7
            uint4 u = *(const uint4*)&vr[dd * 8];
            ushort_t e[8]; unpack8(u, e);
            #pragma unroll
            for (int j = 0; j < 8; ++j) Vt[(dd * 8 + j) * 72 + lane] = e[j];
        }
        if (wave == 0) Vt[64 * 72 + lane] = 0x3F80;     // bf16 1.0 (ones row)
        if (wave == 1) {
            #pragma unroll
            for (int r = 65; r < 80; ++r) Vt[r * 72 + lane] = 0;
        }
        __syncthreads();

        f32x4 acc[5];
        #pragma unroll
        for (int j = 0; j < 5; ++j) acc[j] = z4;
        #pragma unroll
        for (int kt = 0; kt < 2; ++kt) {
            bf16x8 af = *(const bf16x8*)&Kt[(wave * 16 + l15) * 72 + kt * 32 + quad * 8];
            #pragma unroll
            for (int j = 0; j < 5; ++j) {
                bf16x8 bfr = *(const bf16x8*)&Vt[(j * 16 + l15) * 72 + kt * 32 + quad * 8];
                acc[j] = __builtin_amdgcn_mfma_f32_16x16x32_bf16(af, bfr, acc[j], 0, 0, 0);
            }
        }
        ushort_t* outS = SSb + (long)(h * NC + c) * 8192;
        #pragma unroll
        for (int reg = 0; reg < 4; ++reg) {
            int m = wave * 16 + quad * 4 + reg;
            #pragma unroll
            for (int j = 0; j < 4; ++j)
                coh_st16(&outS[m * 64 + j * 16 + l15], f2bf(acc[j][reg]));
            if (l15 == 0) coh_st32(&SSz[(h * NC + c) * M + m], __float_as_uint(acc[4][reg]));
        }
    }
    grid_barrier(bar + 0);

    // ================= phase B: exclusive prefix over chunks ================
    // S handled as dwords: 128 threads x 1 dword column per block.
    {
        if (tid < 128) {
            unsigned* sb32 = (unsigned*)SSb;
            const long hbase = (long)h * NC * 4096;     // dwords
            const int pd = c * 128 + tid;               // dword idx in head slab
            unsigned v[NC];
            #pragma unroll
            for (int cc = 0; cc < NC; ++cc)
                v[cc] = coh_ld32(sb32 + hbase + (long)cc * 4096 + pd);
            float r0 = 0.f, r1 = 0.f;
            #pragma unroll
            for (int cc = 0; cc < NC; ++cc) {
                coh_st32(sb32 + hbase + (long)cc * 4096 + pd, pack2(r0, r1));
                r0 += bf2f((ushort_t)(v[cc] & 0xffff));
                r1 += bf2f((ushort_t)(v[cc] >> 16));
            }
        } else if (c == 0 && tid < 256) {   // z-scan: blocks c==0, 128 threads
            const int m = tid - 128;
            unsigned v[NC];
            #pragma unroll
            for (int cc = 0; cc < NC; ++cc)
                v[cc] = coh_ld32(&SSz[(h * NC + cc) * M + m]);
            float run = 0.f;
            #pragma unroll
            for (int cc = 0; cc < NC; ++cc) {
                coh_st32(&SSz[(h * NC + cc) * M + m], __float_as_uint(run));
                run += __uint_as_float(v[cc]);
            }
        }
    }
    grid_barrier(bar + 1);

    // ================= phase C: causal kernel attention =====================
    {
        const int iw = wave & 3;            // rows tile (16 rows)
        const int nh = wave >> 2;           // cols half (32 cols)

        // coherent loads of S^T source + z (issued first, used after staging)
        const ushort_t* ssb = SSb + (long)(h * NC + c) * 8192;
        const int ms = tid & 127, dg = tid >> 7;     // dg 0..3
        u64_t q0 = coh_ld64(&ssb[ms * 64 + dg * 8]);
        u64_t q1 = coh_ld64(&ssb[ms * 64 + dg * 8 + 4]);
        u64_t q2 = coh_ld64(&ssb[ms * 64 + (4 + dg) * 8]);
        u64_t q3 = coh_ld64(&ssb[ms * 64 + (4 + dg) * 8 + 4]);
        unsigned zv = (tid < 128) ? coh_ld32(&SSz[(h * NC + c) * M + tid]) : 0u;

        for (int t = tid; t < 2048; t += 512) {            // Qp/Kp stage (cached)
            int mat = t >> 10, r = (t >> 4) & 63, c8 = t & 15;
            const ushort_t* src = mat ? KPb : QPb;
            uint4 u = *(const uint4*)&src[((long)(h * L) + c * CT + r) * M + c8 * 8];
            ushort_t* dst = mat ? Kp : Qp;
            *(uint4*)&dst[r * 136 + c8 * 8] = u;
        }
        {   // scatter St[d][m]: q0..q3 = octets dg (2 qwords) and 4+dg
            u64_t qs[4] = {q0, q1, q2, q3};
            #pragma unroll
            for (int k = 0; k < 4; ++k) {
                int d0 = ((k >> 1) ? (4 + dg) : dg) * 8 + (k & 1) * 4;
                #pragma unroll
                for (int e = 0; e < 4; ++e)
                    St[(d0 + e) * 136 + ms] = (ushort_t)(qs[k] >> (16 * e));
            }
        }
        if (tid < 128) St[64 * 136 + tid] = f2bf(__uint_as_float(zv));  // z row
        for (int t = tid; t < 15 * 136; t += 512) St[65 * 136 + t] = 0; // pad
        __syncthreads();

        // phase C1: scores
        f32x4 acc1[2];
        acc1[0] = z4; acc1[1] = z4;
        #pragma unroll
        for (int kt = 0; kt < 4; ++kt) {
            bf16x8 af = *(const bf16x8*)&Qp[(iw * 16 + l15) * 136 + kt * 32 + quad * 8];
            #pragma unroll
            for (int jt = 0; jt < 2; ++jt) {
                bf16x8 bf = *(const bf16x8*)&Kp[(nh * 32 + jt * 16 + l15) * 136 + kt * 32 + quad * 8];
                acc1[jt] = __builtin_amdgcn_mfma_f32_16x16x32_bf16(af, bf, acc1[jt], 0, 0, 0);
            }
        }
        #pragma unroll
        for (int jt = 0; jt < 2; ++jt) {
            int col = nh * 32 + jt * 16 + l15;
            #pragma unroll
            for (int reg = 0; reg < 4; ++reg) {
                int row = iw * 16 + quad * 4 + reg;
                Am[row * 72 + col] = f2bf((col <= row) ? acc1[jt][reg] : 0.f);
            }
        }
        __syncthreads();

        // phase C2: N = [Am|Q'] @ [V;S], den = column 64
        f32x4 acc2[2], acc3;
        acc2[0] = z4; acc2[1] = z4; acc3 = z4;
        #pragma unroll
        for (int kt = 0; kt < 6; ++kt) {
            bf16x8 af = (kt < 2)
                ? *(const bf16x8*)&Am[(iw * 16 + l15) * 72 + kt * 32 + quad * 8]
                : *(const bf16x8*)&Qp[(iw * 16 + l15) * 136 + (kt - 2) * 32 + quad * 8];
            #pragma unroll
            for (int jt = 0; jt < 2; ++jt) {
                int n = nh * 32 + jt * 16 + l15;
                bf16x8 bf = (kt < 2)
                    ? *(const bf16x8*)&Vt[n * 72 + kt * 32 + quad * 8]
                    : *(const bf16x8*)&St[n * 136 + (kt - 2) * 32 + quad * 8];
                acc2[jt] = __builtin_amdgcn_mfma_f32_16x16x32_bf16(af, bf, acc2[jt], 0, 0, 0);
            }
            if (nh == 0) {
                bf16x8 bz = (kt < 2)
                    ? *(const bf16x8*)&Vt[(64 + l15) * 72 + kt * 32 + quad * 8]
                    : *(const bf16x8*)&St[(64 + l15) * 136 + (kt - 2) * 32 + quad * 8];
                acc3 = __builtin_amdgcn_mfma_f32_16x16x32_bf16(af, bz, acc3, 0, 0, 0);
            }
        }
        if (nh == 0 && l15 == 0) {
            #pragma unroll
            for (int reg = 0; reg < 4; ++reg)
                den[iw * 16 + quad * 4 + reg] = acc3[reg];
        }
        __syncthreads();
        #pragma unroll
        for (int jt = 0; jt < 2; ++jt) {
            int d = nh * 32 + jt * 16 + l15;
            #pragma unroll
            for (int reg = 0; reg < 4; ++reg) {
                int row = iw * 16 + quad * 4 + reg;
                coh_st16(&ctxb[(c * CT + row) * DMODEL + h * DH + d],
                         f2bf(acc2[jt][reg] / (den[row] + DEPS)));
            }
        }
    }
    grid_barrier(bar + 2);

    // ================= phase D: output GEMM =================================
    {
        const int ro = bid & 63, co = bid >> 6;
        const int row0 = ro * 32, col0 = co * 128;
        uint4* As8 = (uint4*)SM;                  // [k8][row] stride 33
        uint4* Bs8 = (uint4*)(SM + 4224);         // [k8][col] stride 129
        const int wn = wave & 3, rh = wave >> 2;

        f32x4 acc[2]; acc[0] = z4; acc[1] = z4;
        u64_t qa0 = 0, qa1 = 0; uint4 rb[2];
        auto loadA2 = [&](int ck) {
            if (tid < 256) {
                int row = tid >> 3, k8 = tid & 7;
                const ushort_t* p = &ctxb[(row0 + row) * DMODEL + ck * 64 + k8 * 8];
                qa0 = coh_ld64(p);
                qa1 = coh_ld64(p + 4);
            }
        };
        auto loadB2 = [&](int ck) {
            #pragma unroll
            for (int it = 0; it < 2; ++it) {
                int bt = tid + it * 512;
                int col = bt >> 3, k8 = bt & 7;
                const float4* gp = (const float4*)&Wo[(col0 + col) * DMODEL + ck * 64 + k8 * 8];
                float4 v0 = gp[0], v1 = gp[1];
                rb[it] = make_uint4(pack2(v0.x, v0.y), pack2(v0.z, v0.w),
                                    pack2(v1.x, v1.y), pack2(v1.z, v1.w));
            }
        };

        loadA2(0); loadB2(0);
        for (int ck = 0; ck < 8; ++ck) {
            __syncthreads();
            if (tid < 256)
                As8[(tid & 7) * 33 + (tid >> 3)] =
                    make_uint4((unsigned)qa0, (unsigned)(qa0 >> 32),
                               (unsigned)qa1, (unsigned)(qa1 >> 32));
            #pragma unroll
            for (int it = 0; it < 2; ++it) {
                int bt = tid + it * 512;
                Bs8[(bt & 7) * 129 + (bt >> 3)] = rb[it];
            }
            __syncthreads();
            if (ck < 7) { loadA2(ck + 1); loadB2(ck + 1); }
            const bf16x8* Av = (const bf16x8*)As8;
            const bf16x8* Bv = (const bf16x8*)Bs8;
            #pragma unroll
            for (int kc = 0; kc < 2; ++kc) {
                const int k8 = kc * 4 + quad;
                bf16x8 af = Av[k8 * 33 + rh * 16 + l15];
                bf16x8 b0 = Bv[k8 * 129 + wn * 32 + l15];
                bf16x8 b1 = Bv[k8 * 129 + wn * 32 + 16 + l15];
                acc[0] = __builtin_amdgcn_mfma_f32_16x16x32_bf16(af, b0, acc[0], 0, 0, 0);
                acc[1] = __builtin_amdgcn_mfma_f32_16x16x32_bf16(af, b1, acc[1], 0, 0, 0);
            }
        }
        #pragma unroll
        for (int j = 0; j < 2; ++j) {
            int cc = col0 + wn * 32 + j * 16 + l15;
            float bv_ = bo[cc];
            #pragma unroll
            for (int reg = 0; reg < 4; ++reg) {
                int r = row0 + rh * 16 + quad * 4 + reg;
                out[r * DMODEL + cc] = acc[j][reg] + bv_;
            }
        }
    }
}

extern "C" void kernel_launch(void* const* d_in, const int* in_sizes, int n_in,
                              void* d_out, int out_size, void* d_ws, size_t ws_size,
                              hipStream_t stream)
{
    const float* query = (const float*)d_in[0];
    const float* key_  = (const float*)d_in[1];
    const float* value = (const float*)d_in[2];
    const float* Wq = (const float*)d_in[3];
    const float* bq = (const float*)d_in[4];
    const float* Wk = (const float*)d_in[5];
    const float* bk = (const float*)d_in[6];
    const float* Wv = (const float*)d_in[7];
    const float* bv = (const float*)d_in[8];
    const float* Wo = (const float*)d_in[9];
    const float* bo = (const float*)d_in[10];
    const float* RF = (const float*)d_in[11];

    float* ws = (float*)d_ws;
    ushort_t* Vb   = (ushort_t*)(ws + OFF_VB);
    ushort_t* QPb  = (ushort_t*)(ws + OFF_QPB);
    ushort_t* KPb  = (ushort_t*)(ws + OFF_KPB);
    ushort_t* SSb  = (ushort_t*)(ws + OFF_SSB);
    float* SSz     = ws + OFF_SSZ;
    ushort_t* CTXB = (ushort_t*)(ws + OFF_CTX);
    unsigned* bar  = (unsigned*)(ws + OFF_BAR);

    qkvp_kernel<<<dim3(32, 4, 3), 256, 0, stream>>>(query, key_, value,
                                                    Wq, bq, Wk, bk, Wv, bv, RF,
                                                    Vb, QPb, KPb, bar);
    mega_kernel<<<dim3(NBLK), 512, 0, stream>>>(QPb, KPb, Vb, SSb, SSz, CTXB,
                                                Wo, bo, (float*)d_out, bar);
}